// Round 12
// baseline (1173.848 us; speedup 1.0000x reference)
//
#include <hip/hip_runtime.h>
#include <hip/hip_bf16.h>
#include <stdint.h>

// SAGE (GraphSAGE, LSTM aggregator). f32 I/O, bf16 MFMA internally.
// N=30000, DMAX=16, dims 128 -> 256 -> 64.
// R17 -> R18 (R17 FAILED: system-scope bypass RAISED FETCH 1.70->1.91e6
// (lost gather L2 hits, Whh misses unchanged). Allocation-policy axis dead
// (nt R10, sys-scope R17). Cross-round record: sustained BW scales with
// resident waves (8w: 2.39 -> 16w: 3.1-3.4 TB/s), never near 6.3 ceiling,
// nothing pipe-saturated -> rec2 is OUTSTANDING-REQUEST-limited, not at a
// fabric roofline. Gathers issue in per-pass bursts with dead gaps (MFMA
// chain + barrier drain)):
//   1. Revert to plain gather loads (R13 numerics path).
//   2. F=256: software-pipeline u-gathers, two NAMED buffers (rule #20):
//      ub <- pass-2's u issued BEFORE pass-1 (in flight under pass-1);
//      ua <- NEXT STEP's pass-1 u issued before pass-2 (in flight across
//      pass-2 + the barrier). Per-wave outstanding ~2x, never zero.
//      Reg audit @128/wave: c16+ua16+ub16+ah16+acc32+misc~16 = 112 <= 128.
//      sched_barrier(0) fences pin issue order. Fail tell: WRITE >= 350MB.
//   3. F=128 path unchanged (R13 verbatim).
// Verified layouts (learn_hip m89/m91): A[m=lane&15][k=q*8+j],
// D[row=q*4+r][col=lane&15]; W[4F,F] row-major == gemm-BT B-frag layout.

#define NN 30000
#define DMAXX 16

typedef __bf16 bf16_t;
typedef __bf16 bf16x8 __attribute__((ext_vector_type(8)));
typedef float f32x4 __attribute__((ext_vector_type(4)));
typedef unsigned short u16x4 __attribute__((ext_vector_type(4)));

// persistent scratch (fully rewritten every call; no cross-call state reuse)
__device__ __align__(16) bf16_t g_hbuf[(size_t)NN * 256];    // layer-1 output h1
__device__ __align__(16) bf16_t g_xg1[(size_t)NN * 512];     // feat@Wih1^T + biases
__device__ __align__(16) bf16_t g_xg2[(size_t)NN * 1024];    // h1@Wih2^T + biases
__device__ __align__(16) bf16_t g_wbuf[753664];              // bf16 weight copies
__device__ int g_perm[NN];                                   // degree-sorted node ids

#define OFF_WIH1 0
#define OFF_WHH1 65536
#define OFF_WSELF1 131072
#define OFF_WNEIGH1 163840
#define OFF_WIH2 196608
#define OFF_WHH2 458752
#define OFF_WSELF2 720896
#define OFF_WNEIGH2 737280
#define W_TOTAL 753664

__global__ __launch_bounds__(256)
void cvt_weights(const float* __restrict__ s0, const float* __restrict__ s1,
                 const float* __restrict__ s2, const float* __restrict__ s3,
                 const float* __restrict__ s4, const float* __restrict__ s5,
                 const float* __restrict__ s6, const float* __restrict__ s7)
{
    int i = (blockIdx.x * 256 + threadIdx.x) * 4;
    if (i >= W_TOTAL) return;
    const float* src; int off;
    if      (i < OFF_WHH1)   { src = s0; off = OFF_WIH1; }
    else if (i < OFF_WSELF1) { src = s1; off = OFF_WHH1; }
    else if (i < OFF_WNEIGH1){ src = s2; off = OFF_WSELF1; }
    else if (i < OFF_WIH2)   { src = s3; off = OFF_WNEIGH1; }
    else if (i < OFF_WHH2)   { src = s4; off = OFF_WIH2; }
    else if (i < OFF_WSELF2) { src = s5; off = OFF_WHH2; }
    else if (i < OFF_WNEIGH2){ src = s6; off = OFF_WSELF2; }
    else                     { src = s7; off = OFF_WNEIGH2; }
    float4 v = *reinterpret_cast<const float4*>(src + (i - off));
    bf16_t o[4] __attribute__((aligned(8)));
    o[0] = (bf16_t)v.x; o[1] = (bf16_t)v.y; o[2] = (bf16_t)v.z; o[3] = (bf16_t)v.w;
    *reinterpret_cast<uint2*>(&g_wbuf[i]) = *reinterpret_cast<const uint2*>(o);
}

// counting sort of node ids by DESCENDING degree (LPT block scheduling).
__global__ __launch_bounds__(256)
void build_perm(const int* __restrict__ deg, int* __restrict__ perm)
{
    __shared__ int s_base[DMAXX + 1];
    const int tid = threadIdx.x;
    if (tid <= DMAXX) s_base[tid] = 0;
    __syncthreads();
    for (int i = tid; i < NN; i += 256) {
        int d = deg[i]; d = d < 0 ? 0 : (d > DMAXX ? DMAXX : d);
        atomicAdd(&s_base[d], 1);
    }
    __syncthreads();
    if (tid == 0) {
        int acc = 0;
        for (int d = DMAXX; d >= 0; --d) { int c = s_base[d]; s_base[d] = acc; acc += c; }
    }
    __syncthreads();
    for (int i = tid; i < NN; i += 256) {
        int d = deg[i]; d = d < 0 ? 0 : (d > DMAXX ? DMAXX : d);
        int p = atomicAdd(&s_base[d], 1);
        perm[p] = i;
    }
}

__device__ __forceinline__ float fsig(float x) { return 1.0f / (1.0f + __expf(-x)); }
__device__ __forceinline__ float ftanh(float x) { return 1.0f - 2.0f / (__expf(2.0f * x) + 1.0f); }
__device__ __forceinline__ float bf2f(unsigned short s) {
    union { unsigned u; float f; } v; v.u = ((unsigned)s) << 16; return v.f;
}

// stage a 64-row x-tile (linear rows, row-clamped) into LDS as bf16
template<int F, int LDA, int NT, bool XF32>
__device__ __forceinline__ void stage_tile(bf16_t* dst, const void* src, int row0, int tid)
{
    constexpr int UN = F / 8;          // 16B(bf16) units per row
    for (int e = tid; e < 64 * UN; e += NT) {
        int m = e / UN, sub = e - m * UN;
        int row = row0 + m; if (row >= NN) row = NN - 1;
        if constexpr (XF32) {
            const float* p = (const float*)src + (size_t)row * F + sub * 8;
            float4 f0 = reinterpret_cast<const float4*>(p)[0];
            float4 f1 = reinterpret_cast<const float4*>(p)[1];
            bf16_t t[8] __attribute__((aligned(16)));
            t[0]=(bf16_t)f0.x; t[1]=(bf16_t)f0.y; t[2]=(bf16_t)f0.z; t[3]=(bf16_t)f0.w;
            t[4]=(bf16_t)f1.x; t[5]=(bf16_t)f1.y; t[6]=(bf16_t)f1.z; t[7]=(bf16_t)f1.w;
            *reinterpret_cast<uint4*>(&dst[m * LDA + sub * 8]) = *reinterpret_cast<const uint4*>(t);
        } else {
            const bf16_t* p = (const bf16_t*)src + (size_t)row * F + sub * 8;
            *reinterpret_cast<uint4*>(&dst[m * LDA + sub * 8]) = *reinterpret_cast<const uint4*>(p);
        }
    }
}

// stage a 64-row x-tile with per-row node ids (from LDS array) into LDS
template<int F, int LDA, int NT, bool XF32>
__device__ __forceinline__ void stage_rows(bf16_t* dst, const void* src, const int* nodes, int tid)
{
    constexpr int UN = F / 8;
    for (int e = tid; e < 64 * UN; e += NT) {
        int m = e / UN, sub = e - m * UN;
        int row = nodes[m];
        if constexpr (XF32) {
            const float* p = (const float*)src + (size_t)row * F + sub * 8;
            float4 f0 = reinterpret_cast<const float4*>(p)[0];
            float4 f1 = reinterpret_cast<const float4*>(p)[1];
            bf16_t t[8] __attribute__((aligned(16)));
            t[0]=(bf16_t)f0.x; t[1]=(bf16_t)f0.y; t[2]=(bf16_t)f0.z; t[3]=(bf16_t)f0.w;
            t[4]=(bf16_t)f1.x; t[5]=(bf16_t)f1.y; t[6]=(bf16_t)f1.z; t[7]=(bf16_t)f1.w;
            *reinterpret_cast<uint4*>(&dst[m * LDA + sub * 8]) = *reinterpret_cast<const uint4*>(t);
        } else {
            const bf16_t* p = (const bf16_t*)src + (size_t)row * F + sub * 8;
            *reinterpret_cast<uint4*>(&dst[m * LDA + sub * 8]) = *reinterpret_cast<const uint4*>(p);
        }
    }
}

// xg[N, 4F] (gate-interleaved [c][g]) = x[N,F] @ W[4F,F]^T + b0 + b1
template<int F, int G, int NW, bool XF32>
__global__ __launch_bounds__(NW * 64, 2)
void xg_gemm(const void* __restrict__ xsrc_v, const bf16_t* __restrict__ W,
             const float* __restrict__ b0, const float* __restrict__ b1v,
             bf16_t* __restrict__ xg)
{
    constexpr int LDA = F + 8, KK = F / 32, NT = NW * 64;
    constexpr int CPW = G / NW;        // linear out-cols per wave
    constexpr int CT = CPW / 16;
    static_assert(CPW % 16 == 0 && F % 16 == 0, "");
    const int tid = threadIdx.x, wave = tid >> 6, lane = tid & 63;
    const int q = lane >> 4, m16 = lane & 15;
    const int row0 = blockIdx.x * 64;

    __shared__ __align__(16) bf16_t s_x[64 * LDA];
    stage_tile<F, LDA, NT, XF32>(s_x, xsrc_v, row0, tid);
    __syncthreads();

    #pragma unroll
    for (int ct = 0; ct < CT; ++ct) {
        const int lc0 = wave * CPW + ct * 16;   // linear col block (within one gate)
        const int g = lc0 / F, c0 = lc0 - g * F;
        const float bias = b0[lc0 + m16] + b1v[lc0 + m16];
        f32x4 acc[4];
        #pragma unroll
        for (int rt = 0; rt < 4; ++rt)
            #pragma unroll
            for (int r = 0; r < 4; ++r) acc[rt][r] = bias;
        #pragma unroll
        for (int kk = 0; kk < KK; ++kk) {
            const int ko = kk * 32 + q * 8;
            bf16x8 b = *reinterpret_cast<const bf16x8*>(W + (size_t)(lc0 + m16) * F + ko);
            #pragma unroll
            for (int rt = 0; rt < 4; ++rt) {
                bf16x8 a = *reinterpret_cast<const bf16x8*>(&s_x[(rt * 16 + m16) * LDA + ko]);
                acc[rt] = __builtin_amdgcn_mfma_f32_16x16x32_bf16(a, b, acc[rt], 0, 0, 0);
            }
        }
        #pragma unroll
        for (int rt = 0; rt < 4; ++rt)
            #pragma unroll
            for (int r = 0; r < 4; ++r) {
                int row = row0 + rt * 16 + q * 4 + r;
                if (row < NN)
                    xg[(size_t)row * G + (size_t)(c0 + m16) * 4 + g] = (bf16_t)acc[rt][r];
            }
    }
}

// LSTM recurrence over gathered neighbors + fused fc epilogue.
// Block b: nodes perm[b*64 .. b*64+63] (degree-sorted DESC), loops to
// tmax = max(deg in block). 16 waves = NWR row-groups x NWC col-waves.
// Each step runs NPASS passes of 2 row-tiles; F=256 pipelines the u-gathers
// (ub in flight under pass 1; ua refill in flight across pass 2 + barrier).
// gates = gather(xg) + h @ Whh^T ; out = x_self@Wself^T + h_fin@Wneigh^T + b
template<int F, int OUTF, bool RELU, bool XF32, typename OutT>
__global__ __launch_bounds__(1024, 4)
void sage_rec(const void* __restrict__ xself_v,
              const bf16_t* __restrict__ xg,
              const int* __restrict__ nbr_idx, const int* __restrict__ deg,
              const int* __restrict__ perm,
              const bf16_t* __restrict__ Whh,
              const bf16_t* __restrict__ Wself, const bf16_t* __restrict__ Wneigh,
              const float* __restrict__ bout, OutT* __restrict__ outp)
{
    constexpr int M = 64, LDA = F + 8, KK = F / 32, NW = 16, NT = 1024;
    constexpr int NWC = F / 16;            // col-waves, 16 cols each
    constexpr int NWR = NW / NWC;          // row-groups (1 for F=256, 2 for F=128)
    constexpr int RT = M / (16 * NWR);     // row-tiles per wave (4 or 2)
    constexpr int NPASS = RT / 2;          // 2 row-tiles per pass
    constexpr int G4 = 4 * F;
    static_assert(NWC * NWR == NW && RT % 2 == 0, "");
    const int tid = threadIdx.x, wave = tid >> 6, lane = tid & 63;
    const int q = lane >> 4, m16 = lane & 15;
    const int wc = wave % NWC, wr = wave / NWC;
    const int ROWB = wr * (RT * 16);       // this wave's row base in tile
    const int col = wc * 16 + m16;         // this lane's output column (per gate)
    const int slot0 = blockIdx.x * M;

    __shared__ __align__(16) bf16_t s_h[2][M * LDA];   // double-buffered h
    __shared__ int s_idx[M * DMAXX];
    __shared__ int s_deg[M];
    __shared__ int s_node[M];
    __shared__ int s_tmax;

    for (int i = tid; i < M; i += NT) {
        int slot = slot0 + i; if (slot >= NN) slot = NN - 1;
        int node = perm[slot];
        s_node[i] = node;
        s_deg[i] = deg[node];
    }
    __syncthreads();
    for (int i = tid; i < M * DMAXX; i += NT) {
        int node = s_node[i >> 4];
        int v = nbr_idx[node * DMAXX + (i & 15)];
        if (v < 0) v = 0; if (v >= NN) v = NN - 1;
        s_idx[i] = v;
    }
    for (int i = tid; i < M * LDA; i += NT) s_h[0][i] = (bf16_t)0.0f;
    if (tid == 0) {
        int mx = 1;
        for (int i = 0; i < M; ++i) { int d = s_deg[i]; mx = d > mx ? d : mx; }
        s_tmax = mx;
    }
    __syncthreads();
    const int tmax = s_tmax;   // uniform-degree blocks: ~= block's degree bucket

    // persistent cell state: one f32x4 per row-tile (named, never runtime-indexed)
    f32x4 c0, c1, c2, c3;
    #pragma unroll
    for (int r = 0; r < 4; ++r) { c0[r]=0.f; c1[r]=0.f; c2[r]=0.f; c3[r]=0.f; }

    // gather u (xg gate-init) for 2 row-tiles starting at rtb into regs
    auto ld_u = [&](int rtb, int t, u16x4 uu[2][4]) {
        #pragma unroll
        for (int j = 0; j < 2; ++j)
            #pragma unroll
            for (int r = 0; r < 4; ++r) {
                int row = s_idx[(ROWB + (rtb + j) * 16 + q * 4 + r) * DMAXX + t];
                uu[j][r] = *reinterpret_cast<const u16x4*>(
                    xg + (size_t)row * G4 + (size_t)col * 4);
            }
    };

    // one pass: 2 row-tiles (rtb, rtb+1) x all 4 gates, u preloaded by caller
    auto do_pass = [&](int rtb, f32x4& cA, f32x4& cB, const u16x4 uu[2][4],
                       const bf16_t* cur, bf16_t* nxt, int t) {
        f32x4 acc[2][4];
        #pragma unroll
        for (int j = 0; j < 2; ++j)
            #pragma unroll
            for (int g = 0; g < 4; ++g)
                #pragma unroll
                for (int r = 0; r < 4; ++r) acc[j][g][r] = 0.0f;
        #pragma unroll
        for (int kk = 0; kk < KK; ++kk) {
            const int ko = kk * 32 + q * 8;
            bf16x8 ah0 = *reinterpret_cast<const bf16x8*>(
                &cur[(ROWB + rtb * 16 + m16) * LDA + ko]);
            bf16x8 ah1 = *reinterpret_cast<const bf16x8*>(
                &cur[(ROWB + (rtb + 1) * 16 + m16) * LDA + ko]);
            #pragma unroll
            for (int g = 0; g < 4; ++g) {
                bf16x8 bh = *reinterpret_cast<const bf16x8*>(
                    Whh + (size_t)(g * F + col) * F + ko);
                acc[0][g] = __builtin_amdgcn_mfma_f32_16x16x32_bf16(ah0, bh, acc[0][g], 0, 0, 0);
                acc[1][g] = __builtin_amdgcn_mfma_f32_16x16x32_bf16(ah1, bh, acc[1][g], 0, 0, 0);
            }
        }
        // pointwise LSTM update + masked store:
        //   t <  deg : write h_new (and update c)
        //   t == deg : copy frozen h from cur (this thread's t-1 write)
        //   t >  deg : skip -- nxt already holds the frozen value
        #pragma unroll
        for (int j = 0; j < 2; ++j) {
            f32x4& cc = j ? cB : cA;
            #pragma unroll
            for (int r = 0; r < 4; ++r) {
                int rowr = ROWB + (rtb + j) * 16 + q * 4 + r;
                float iv = fsig (acc[j][0][r] + bf2f(uu[j][r].x));
                float fv = fsig (acc[j][1][r] + bf2f(uu[j][r].y));
                float gv = ftanh(acc[j][2][r] + bf2f(uu[j][r].z));
                float ov = fsig (acc[j][3][r] + bf2f(uu[j][r].w));
                float cn = fv * cc[r] + iv * gv;
                float hv = ov * ftanh(cn);
                const int pos = rowr * LDA + col;
                int d = s_deg[rowr];
                if (t < d) {
                    cc[r] = cn;
                    nxt[pos] = (bf16_t)hv;
                } else if (t == d) {
                    reinterpret_cast<unsigned short*>(nxt)[pos] =
                        reinterpret_cast<const unsigned short*>(cur)[pos];
                }
            }
        }
    };

    u16x4 ua[2][4], ub[2][4];
    if (tmax > 0) ld_u(0, 0, ua);          // prologue: pass-1 u for step 0

    #pragma unroll 1
    for (int t = 0; t < tmax; ++t) {
        const bf16_t* cur = s_h[t & 1];
        bf16_t* nxt = s_h[(t + 1) & 1];
        if constexpr (NPASS > 1) {
            ld_u(2, t, ub);                          // in flight under pass 1
            __builtin_amdgcn_sched_barrier(0);
            do_pass(0, c0, c1, ua, cur, nxt, t);
            __builtin_amdgcn_sched_barrier(0);
            if (t + 1 < tmax) ld_u(0, t + 1, ua);    // in flight across pass 2 + barrier
            __builtin_amdgcn_sched_barrier(0);
            do_pass(2, c2, c3, ub, cur, nxt, t);
        } else {
            do_pass(0, c0, c1, ua, cur, nxt, t);
            if (t + 1 < tmax) ld_u(0, t + 1, ua);    // refill across barrier
        }
        __syncthreads();   // nxt fully written; cur fully consumed
    }

    // final h is in s_h[tmax&1]; stage self-rows into the other buffer
    const int fb = tmax & 1;
    const bf16_t* hfin = s_h[fb];
    bf16_t* hstage = s_h[fb ^ 1];
    stage_rows<F, LDA, NT, XF32>(hstage, xself_v, s_node, tid);
    __syncthreads();

    // epilogue: out = x_self @ Wself^T + h_fin @ Wneigh^T + bout (+relu)
    constexpr int NCT = OUTF / 16;
    constexpr int TILES = NCT * 4;     // 4 row-tiles of the 64-node tile
    constexpr int TPW = TILES / NW;
    static_assert(TILES % NW == 0, "");
    #pragma unroll
    for (int tt = 0; tt < TPW; ++tt) {
        int tile = wave * TPW + tt;
        int ot = tile % NCT, rt = tile / NCT;
        f32x4 o;
        o[0] = 0.f; o[1] = 0.f; o[2] = 0.f; o[3] = 0.f;
        #pragma unroll
        for (int kk = 0; kk < KK; ++kk) {
            const int ko = kk * 32 + q * 8;
            bf16x8 axs = *reinterpret_cast<const bf16x8*>(&hstage[(rt * 16 + m16) * LDA + ko]);
            bf16x8 am  = *reinterpret_cast<const bf16x8*>(&hfin[(rt * 16 + m16) * LDA + ko]);
            bf16x8 bs = *reinterpret_cast<const bf16x8*>(Wself  + (size_t)(ot * 16 + m16) * F + ko);
            bf16x8 bn = *reinterpret_cast<const bf16x8*>(Wneigh + (size_t)(ot * 16 + m16) * F + ko);
            o = __builtin_amdgcn_mfma_f32_16x16x32_bf16(axs, bs, o, 0, 0, 0);
            o = __builtin_amdgcn_mfma_f32_16x16x32_bf16(am,  bn, o, 0, 0, 0);
        }
        int ocol = ot * 16 + m16;
        float bias = bout[ocol];
        #pragma unroll
        for (int r = 0; r < 4; ++r) {
            int node = s_node[rt * 16 + q * 4 + r];
            float v = o[r] + bias;
            if (RELU) v = fmaxf(v, 0.0f);
            outp[(size_t)node * OUTF + ocol] = (OutT)v;
        }
    }
}

extern "C" void kernel_launch(void* const* d_in, const int* in_sizes, int n_in,
                              void* d_out, int out_size, void* d_ws, size_t ws_size,
                              hipStream_t stream)
{
    const float* feat    = (const float*)d_in[0];
    const int*   nbr     = (const int*)d_in[1];
    const int*   degp    = (const int*)d_in[2];
    const float* Wih1    = (const float*)d_in[3];
    const float* Whh1    = (const float*)d_in[4];
    const float* bih1    = (const float*)d_in[5];
    const float* bhh1    = (const float*)d_in[6];
    const float* Wself1  = (const float*)d_in[7];
    const float* Wneigh1 = (const float*)d_in[8];
    const float* b1      = (const float*)d_in[9];
    const float* Wih2    = (const float*)d_in[10];
    const float* Whh2    = (const float*)d_in[11];
    const float* bih2    = (const float*)d_in[12];
    const float* bhh2    = (const float*)d_in[13];
    const float* Wself2  = (const float*)d_in[14];
    const float* Wneigh2 = (const float*)d_in[15];
    const float* b2      = (const float*)d_in[16];

    bf16_t *hglob, *wglob, *xg1, *xg2;
    int *permg;
    hipGetSymbolAddress((void**)&hglob, HIP_SYMBOL(g_hbuf));
    hipGetSymbolAddress((void**)&wglob, HIP_SYMBOL(g_wbuf));
    hipGetSymbolAddress((void**)&xg1,   HIP_SYMBOL(g_xg1));
    hipGetSymbolAddress((void**)&xg2,   HIP_SYMBOL(g_xg2));
    hipGetSymbolAddress((void**)&permg, HIP_SYMBOL(g_perm));

    cvt_weights<<<W_TOTAL / 4 / 256, 256, 0, stream>>>(
        Wih1, Whh1, Wself1, Wneigh1, Wih2, Whh2, Wself2, Wneigh2);

    build_perm<<<1, 256, 0, stream>>>(degp, permg);

    const int grid = (NN + 63) / 64;   // 469 WGs

    xg_gemm<128, 512, 8, true><<<grid, 512, 0, stream>>>(
        feat, wglob + OFF_WIH1, bih1, bhh1, xg1);

    sage_rec<128, 256, true, true, bf16_t><<<grid, 1024, 0, stream>>>(
        feat, xg1, nbr, degp, permg, wglob + OFF_WHH1,
        wglob + OFF_WSELF1, wglob + OFF_WNEIGH1, b1, hglob);

    xg_gemm<256, 1024, 8, false><<<grid, 512, 0, stream>>>(
        hglob, wglob + OFF_WIH2, bih2, bhh2, xg2);

    sage_rec<256, 64, false, false, float><<<grid, 1024, 0, stream>>>(
        hglob, xg2, nbr, degp, permg, wglob + OFF_WHH2,
        wglob + OFF_WSELF2, wglob + OFF_WNEIGH2, b2, (float*)d_out);
}

// Round 14
// 1082.814 us; speedup vs baseline: 1.0841x; 1.0841x over previous
//
#include <hip/hip_runtime.h>
#include <hip/hip_bf16.h>
#include <stdint.h>

// SAGE (GraphSAGE, LSTM aggregator). f32 I/O, bf16 MFMA internally.
// N=30000, DMAX=16, dims 128 -> 256 -> 64.
// R19 RESUBMIT (R19 bench = infra failure "container failed twice", same
// signature as R12 which ran fine on unchanged resubmit. Kernel-side audit:
// LDS 138.8KB < 160KB (static >64KB proven launchable R11-R18), geometry
// unchanged -> no kernel-side cause; resubmit for the measurement).
// R18 -> R19 (R18 FAILED the pre-registered tell: WRITE 609MB = spill.
// Resource model now solid: 1024-thr blocks force 16 waves/CU -> HW caps
// 512/4 = 128 unified regs/wave; acc32+c16+transients fill it, any +16
// prefetch spills. BW did rise to 3.45 TB/s (outstanding-requests theory
// mechanistically right) but spill bytes ate it. R15/R16 showed the 4-tile
// single pass saves ~425MB demand-FETCH (Whh issue 4->2GB) but spilled by
// ~16 regs):
//   1. Move cell state c to LDS as f32 (s_c[64][260], 66.6KB; total LDS
//      ~139KB < 160KB; occupancy unchanged -- VGPR is the binding cap).
//      (row,col) is lane-exclusive -> no races. BIT-IDENTICAL numerics.
//   2. F=256: single 4-row-tile pass (Whh B-frag loaded once per 4 A-frags),
//      u gathered per-tile double-buffered AFTER the MFMA chain.
//      Reg audit: MFMA phase acc64+ah32+bh8+addr12 ~= 116; pointwise
//      acc64+u16+misc ~= 90. Both <= 128.
//   3. rec1 (F=128) = R13 verbatim. FAIL TELL: WRITE >= 350MB -> revert R13.
// Verified layouts (learn_hip m89/m91): A[m=lane&15][k=q*8+j],
// D[row=q*4+r][col=lane&15]; W[4F,F] row-major == gemm-BT B-frag layout.

#define NN 30000
#define DMAXX 16

typedef __bf16 bf16_t;
typedef __bf16 bf16x8 __attribute__((ext_vector_type(8)));
typedef float f32x4 __attribute__((ext_vector_type(4)));
typedef unsigned short u16x4 __attribute__((ext_vector_type(4)));

// persistent scratch (fully rewritten every call; no cross-call state reuse)
__device__ __align__(16) bf16_t g_hbuf[(size_t)NN * 256];    // layer-1 output h1
__device__ __align__(16) bf16_t g_xg1[(size_t)NN * 512];     // feat@Wih1^T + biases
__device__ __align__(16) bf16_t g_xg2[(size_t)NN * 1024];    // h1@Wih2^T + biases
__device__ __align__(16) bf16_t g_wbuf[753664];              // bf16 weight copies
__device__ int g_perm[NN];                                   // degree-sorted node ids

#define OFF_WIH1 0
#define OFF_WHH1 65536
#define OFF_WSELF1 131072
#define OFF_WNEIGH1 163840
#define OFF_WIH2 196608
#define OFF_WHH2 458752
#define OFF_WSELF2 720896
#define OFF_WNEIGH2 737280
#define W_TOTAL 753664

__global__ __launch_bounds__(256)
void cvt_weights(const float* __restrict__ s0, const float* __restrict__ s1,
                 const float* __restrict__ s2, const float* __restrict__ s3,
                 const float* __restrict__ s4, const float* __restrict__ s5,
                 const float* __restrict__ s6, const float* __restrict__ s7)
{
    int i = (blockIdx.x * 256 + threadIdx.x) * 4;
    if (i >= W_TOTAL) return;
    const float* src; int off;
    if      (i < OFF_WHH1)   { src = s0; off = OFF_WIH1; }
    else if (i < OFF_WSELF1) { src = s1; off = OFF_WHH1; }
    else if (i < OFF_WNEIGH1){ src = s2; off = OFF_WSELF1; }
    else if (i < OFF_WIH2)   { src = s3; off = OFF_WNEIGH1; }
    else if (i < OFF_WHH2)   { src = s4; off = OFF_WIH2; }
    else if (i < OFF_WSELF2) { src = s5; off = OFF_WHH2; }
    else if (i < OFF_WNEIGH2){ src = s6; off = OFF_WSELF2; }
    else                     { src = s7; off = OFF_WNEIGH2; }
    float4 v = *reinterpret_cast<const float4*>(src + (i - off));
    bf16_t o[4] __attribute__((aligned(8)));
    o[0] = (bf16_t)v.x; o[1] = (bf16_t)v.y; o[2] = (bf16_t)v.z; o[3] = (bf16_t)v.w;
    *reinterpret_cast<uint2*>(&g_wbuf[i]) = *reinterpret_cast<const uint2*>(o);
}

// counting sort of node ids by DESCENDING degree (LPT block scheduling).
__global__ __launch_bounds__(256)
void build_perm(const int* __restrict__ deg, int* __restrict__ perm)
{
    __shared__ int s_base[DMAXX + 1];
    const int tid = threadIdx.x;
    if (tid <= DMAXX) s_base[tid] = 0;
    __syncthreads();
    for (int i = tid; i < NN; i += 256) {
        int d = deg[i]; d = d < 0 ? 0 : (d > DMAXX ? DMAXX : d);
        atomicAdd(&s_base[d], 1);
    }
    __syncthreads();
    if (tid == 0) {
        int acc = 0;
        for (int d = DMAXX; d >= 0; --d) { int c = s_base[d]; s_base[d] = acc; acc += c; }
    }
    __syncthreads();
    for (int i = tid; i < NN; i += 256) {
        int d = deg[i]; d = d < 0 ? 0 : (d > DMAXX ? DMAXX : d);
        int p = atomicAdd(&s_base[d], 1);
        perm[p] = i;
    }
}

__device__ __forceinline__ float fsig(float x) { return 1.0f / (1.0f + __expf(-x)); }
__device__ __forceinline__ float ftanh(float x) { return 1.0f - 2.0f / (__expf(2.0f * x) + 1.0f); }
__device__ __forceinline__ float bf2f(unsigned short s) {
    union { unsigned u; float f; } v; v.u = ((unsigned)s) << 16; return v.f;
}

// stage a 64-row x-tile (linear rows, row-clamped) into LDS as bf16
template<int F, int LDA, int NT, bool XF32>
__device__ __forceinline__ void stage_tile(bf16_t* dst, const void* src, int row0, int tid)
{
    constexpr int UN = F / 8;          // 16B(bf16) units per row
    for (int e = tid; e < 64 * UN; e += NT) {
        int m = e / UN, sub = e - m * UN;
        int row = row0 + m; if (row >= NN) row = NN - 1;
        if constexpr (XF32) {
            const float* p = (const float*)src + (size_t)row * F + sub * 8;
            float4 f0 = reinterpret_cast<const float4*>(p)[0];
            float4 f1 = reinterpret_cast<const float4*>(p)[1];
            bf16_t t[8] __attribute__((aligned(16)));
            t[0]=(bf16_t)f0.x; t[1]=(bf16_t)f0.y; t[2]=(bf16_t)f0.z; t[3]=(bf16_t)f0.w;
            t[4]=(bf16_t)f1.x; t[5]=(bf16_t)f1.y; t[6]=(bf16_t)f1.z; t[7]=(bf16_t)f1.w;
            *reinterpret_cast<uint4*>(&dst[m * LDA + sub * 8]) = *reinterpret_cast<const uint4*>(t);
        } else {
            const bf16_t* p = (const bf16_t*)src + (size_t)row * F + sub * 8;
            *reinterpret_cast<uint4*>(&dst[m * LDA + sub * 8]) = *reinterpret_cast<const uint4*>(p);
        }
    }
}

// stage a 64-row x-tile with per-row node ids (from LDS array) into LDS
template<int F, int LDA, int NT, bool XF32>
__device__ __forceinline__ void stage_rows(bf16_t* dst, const void* src, const int* nodes, int tid)
{
    constexpr int UN = F / 8;
    for (int e = tid; e < 64 * UN; e += NT) {
        int m = e / UN, sub = e - m * UN;
        int row = nodes[m];
        if constexpr (XF32) {
            const float* p = (const float*)src + (size_t)row * F + sub * 8;
            float4 f0 = reinterpret_cast<const float4*>(p)[0];
            float4 f1 = reinterpret_cast<const float4*>(p)[1];
            bf16_t t[8] __attribute__((aligned(16)));
            t[0]=(bf16_t)f0.x; t[1]=(bf16_t)f0.y; t[2]=(bf16_t)f0.z; t[3]=(bf16_t)f0.w;
            t[4]=(bf16_t)f1.x; t[5]=(bf16_t)f1.y; t[6]=(bf16_t)f1.z; t[7]=(bf16_t)f1.w;
            *reinterpret_cast<uint4*>(&dst[m * LDA + sub * 8]) = *reinterpret_cast<const uint4*>(t);
        } else {
            const bf16_t* p = (const bf16_t*)src + (size_t)row * F + sub * 8;
            *reinterpret_cast<uint4*>(&dst[m * LDA + sub * 8]) = *reinterpret_cast<const uint4*>(p);
        }
    }
}

// xg[N, 4F] (gate-interleaved [c][g]) = x[N,F] @ W[4F,F]^T + b0 + b1
template<int F, int G, int NW, bool XF32>
__global__ __launch_bounds__(NW * 64, 2)
void xg_gemm(const void* __restrict__ xsrc_v, const bf16_t* __restrict__ W,
             const float* __restrict__ b0, const float* __restrict__ b1v,
             bf16_t* __restrict__ xg)
{
    constexpr int LDA = F + 8, KK = F / 32, NT = NW * 64;
    constexpr int CPW = G / NW;        // linear out-cols per wave
    constexpr int CT = CPW / 16;
    static_assert(CPW % 16 == 0 && F % 16 == 0, "");
    const int tid = threadIdx.x, wave = tid >> 6, lane = tid & 63;
    const int q = lane >> 4, m16 = lane & 15;
    const int row0 = blockIdx.x * 64;

    __shared__ __align__(16) bf16_t s_x[64 * LDA];
    stage_tile<F, LDA, NT, XF32>(s_x, xsrc_v, row0, tid);
    __syncthreads();

    #pragma unroll
    for (int ct = 0; ct < CT; ++ct) {
        const int lc0 = wave * CPW + ct * 16;   // linear col block (within one gate)
        const int g = lc0 / F, c0 = lc0 - g * F;
        const float bias = b0[lc0 + m16] + b1v[lc0 + m16];
        f32x4 acc[4];
        #pragma unroll
        for (int rt = 0; rt < 4; ++rt)
            #pragma unroll
            for (int r = 0; r < 4; ++r) acc[rt][r] = bias;
        #pragma unroll
        for (int kk = 0; kk < KK; ++kk) {
            const int ko = kk * 32 + q * 8;
            bf16x8 b = *reinterpret_cast<const bf16x8*>(W + (size_t)(lc0 + m16) * F + ko);
            #pragma unroll
            for (int rt = 0; rt < 4; ++rt) {
                bf16x8 a = *reinterpret_cast<const bf16x8*>(&s_x[(rt * 16 + m16) * LDA + ko]);
                acc[rt] = __builtin_amdgcn_mfma_f32_16x16x32_bf16(a, b, acc[rt], 0, 0, 0);
            }
        }
        #pragma unroll
        for (int rt = 0; rt < 4; ++rt)
            #pragma unroll
            for (int r = 0; r < 4; ++r) {
                int row = row0 + rt * 16 + q * 4 + r;
                if (row < NN)
                    xg[(size_t)row * G + (size_t)(c0 + m16) * 4 + g] = (bf16_t)acc[rt][r];
            }
    }
}

// LSTM recurrence over gathered neighbors + fused fc epilogue.
// Block b: nodes perm[b*64 .. b*64+63] (degree-sorted DESC), loops to
// tmax = max(deg in block). 16 waves = NWR row-groups x NWC col-waves.
// F=256: ONE 4-row-tile pass per step (Whh B-frag loaded once per 4
//        A-frags), cell state c in LDS (f32, exact), u gathered per-tile
//        double-buffered after the MFMA chain.
// F=128: one 2-row-tile pass, c in registers (R13-identical).
// gates = gather(xg) + h @ Whh^T ; out = x_self@Wself^T + h_fin@Wneigh^T + b
template<int F, int OUTF, bool RELU, bool XF32, typename OutT>
__global__ __launch_bounds__(1024, 4)
void sage_rec(const void* __restrict__ xself_v,
              const bf16_t* __restrict__ xg,
              const int* __restrict__ nbr_idx, const int* __restrict__ deg,
              const int* __restrict__ perm,
              const bf16_t* __restrict__ Whh,
              const bf16_t* __restrict__ Wself, const bf16_t* __restrict__ Wneigh,
              const float* __restrict__ bout, OutT* __restrict__ outp)
{
    constexpr int M = 64, LDA = F + 8, KK = F / 32, NW = 16, NT = 1024;
    constexpr int NWC = F / 16;            // col-waves, 16 cols each
    constexpr int NWR = NW / NWC;          // row-groups (1 for F=256, 2 for F=128)
    constexpr int RT = M / (16 * NWR);     // row-tiles per wave (4 or 2)
    constexpr int G4 = 4 * F;
    constexpr int CPAD = 260;              // s_c row pitch (f32), bank-spread
    static_assert(NWC * NWR == NW && (RT == 2 || RT == 4), "");
    const int tid = threadIdx.x, wave = tid >> 6, lane = tid & 63;
    const int q = lane >> 4, m16 = lane & 15;
    const int wc = wave % NWC, wr = wave / NWC;
    const int ROWB = wr * (RT * 16);       // this wave's row base in tile
    const int col = wc * 16 + m16;         // this lane's output column (per gate)
    const int slot0 = blockIdx.x * M;

    __shared__ __align__(16) bf16_t s_h[2][M * LDA];   // double-buffered h
    __shared__ float s_c[(RT == 4) ? (M * CPAD) : 1];  // cell state (F=256 path)
    __shared__ int s_idx[M * DMAXX];
    __shared__ int s_deg[M];
    __shared__ int s_node[M];
    __shared__ int s_tmax;

    for (int i = tid; i < M; i += NT) {
        int slot = slot0 + i; if (slot >= NN) slot = NN - 1;
        int node = perm[slot];
        s_node[i] = node;
        s_deg[i] = deg[node];
    }
    __syncthreads();
    for (int i = tid; i < M * DMAXX; i += NT) {
        int node = s_node[i >> 4];
        int v = nbr_idx[node * DMAXX + (i & 15)];
        if (v < 0) v = 0; if (v >= NN) v = NN - 1;
        s_idx[i] = v;
    }
    for (int i = tid; i < M * LDA; i += NT) s_h[0][i] = (bf16_t)0.0f;
    if constexpr (RT == 4) {
        for (int i = tid; i < M * CPAD; i += NT) s_c[i] = 0.0f;
    }
    if (tid == 0) {
        int mx = 1;
        for (int i = 0; i < M; ++i) { int d = s_deg[i]; mx = d > mx ? d : mx; }
        s_tmax = mx;
    }
    __syncthreads();
    const int tmax = s_tmax;   // uniform-degree blocks: ~= block's degree bucket

    // persistent cell state for the F=128 path (named, never runtime-indexed)
    f32x4 c0, c1;
    #pragma unroll
    for (int r = 0; r < 4; ++r) { c0[r]=0.f; c1[r]=0.f; }

    // gather u (xg gate-init) for ONE row-tile into 4 u16x4 regs
    auto ld_u1 = [&](int rtile, int t, u16x4* uu) {
        #pragma unroll
        for (int r = 0; r < 4; ++r) {
            int row = s_idx[(ROWB + rtile * 16 + q * 4 + r) * DMAXX + t];
            uu[r] = *reinterpret_cast<const u16x4*>(
                xg + (size_t)row * G4 + (size_t)col * 4);
        }
    };

    // F=128 path: one pass of 2 row-tiles, c in registers (R13-identical)
    auto do_pass2 = [&](const bf16_t* cur, bf16_t* nxt, int t) {
        u16x4 u[2][4];
        ld_u1(0, t, u[0]);
        ld_u1(1, t, u[1]);
        f32x4 acc[2][4];
        #pragma unroll
        for (int j = 0; j < 2; ++j)
            #pragma unroll
            for (int g = 0; g < 4; ++g)
                #pragma unroll
                for (int r = 0; r < 4; ++r) acc[j][g][r] = 0.0f;
        #pragma unroll
        for (int kk = 0; kk < KK; ++kk) {
            const int ko = kk * 32 + q * 8;
            bf16x8 ah0 = *reinterpret_cast<const bf16x8*>(&cur[(ROWB + m16) * LDA + ko]);
            bf16x8 ah1 = *reinterpret_cast<const bf16x8*>(&cur[(ROWB + 16 + m16) * LDA + ko]);
            #pragma unroll
            for (int g = 0; g < 4; ++g) {
                bf16x8 bh = *reinterpret_cast<const bf16x8*>(
                    Whh + (size_t)(g * F + col) * F + ko);
                acc[0][g] = __builtin_amdgcn_mfma_f32_16x16x32_bf16(ah0, bh, acc[0][g], 0, 0, 0);
                acc[1][g] = __builtin_amdgcn_mfma_f32_16x16x32_bf16(ah1, bh, acc[1][g], 0, 0, 0);
            }
        }
        #pragma unroll
        for (int j = 0; j < 2; ++j) {
            f32x4& cc = j ? c1 : c0;
            #pragma unroll
            for (int r = 0; r < 4; ++r) {
                int rowr = ROWB + j * 16 + q * 4 + r;
                float iv = fsig (acc[j][0][r] + bf2f(u[j][r].x));
                float fv = fsig (acc[j][1][r] + bf2f(u[j][r].y));
                float gv = ftanh(acc[j][2][r] + bf2f(u[j][r].z));
                float ov = fsig (acc[j][3][r] + bf2f(u[j][r].w));
                float cn = fv * cc[r] + iv * gv;
                float hv = ov * ftanh(cn);
                const int pos = rowr * LDA + col;
                int d = s_deg[rowr];
                if (t < d) {
                    cc[r] = cn;
                    nxt[pos] = (bf16_t)hv;
                } else if (t == d) {
                    reinterpret_cast<unsigned short*>(nxt)[pos] =
                        reinterpret_cast<const unsigned short*>(cur)[pos];
                }
            }
        }
    };

    // F=256 path: ONE pass of 4 row-tiles; c in LDS; u per-tile double-buffered
    // after the MFMA chain (sched_barrier fences pin issue order; loads of
    // tile j+1 fly under pointwise j).
    auto do_pass4 = [&](const bf16_t* cur, bf16_t* nxt, int t) {
        f32x4 acc[4][4];
        #pragma unroll
        for (int j = 0; j < 4; ++j)
            #pragma unroll
            for (int g = 0; g < 4; ++g)
                #pragma unroll
                for (int r = 0; r < 4; ++r) acc[j][g][r] = 0.0f;
        #pragma unroll
        for (int kk = 0; kk < KK; ++kk) {
            const int ko = kk * 32 + q * 8;
            bf16x8 a0 = *reinterpret_cast<const bf16x8*>(&cur[(m16) * LDA + ko]);
            bf16x8 a1 = *reinterpret_cast<const bf16x8*>(&cur[(16 + m16) * LDA + ko]);
            bf16x8 a2 = *reinterpret_cast<const bf16x8*>(&cur[(32 + m16) * LDA + ko]);
            bf16x8 a3 = *reinterpret_cast<const bf16x8*>(&cur[(48 + m16) * LDA + ko]);
            #pragma unroll
            for (int g = 0; g < 4; ++g) {
                bf16x8 bh = *reinterpret_cast<const bf16x8*>(
                    Whh + (size_t)(g * F + col) * F + ko);
                acc[0][g] = __builtin_amdgcn_mfma_f32_16x16x32_bf16(a0, bh, acc[0][g], 0, 0, 0);
                acc[1][g] = __builtin_amdgcn_mfma_f32_16x16x32_bf16(a1, bh, acc[1][g], 0, 0, 0);
                acc[2][g] = __builtin_amdgcn_mfma_f32_16x16x32_bf16(a2, bh, acc[2][g], 0, 0, 0);
                acc[3][g] = __builtin_amdgcn_mfma_f32_16x16x32_bf16(a3, bh, acc[3][g], 0, 0, 0);
            }
        }
        __builtin_amdgcn_sched_barrier(0);   // fence: u loads stay out of MFMA phase
        u16x4 uA[4], uB[4];
        ld_u1(0, t, uA);
        #pragma unroll
        for (int j = 0; j < 4; ++j) {
            u16x4* ucur = (j & 1) ? uB : uA;
            u16x4* unxt = (j & 1) ? uA : uB;
            if (j + 1 < 4) ld_u1(j + 1, t, unxt);   // flies under pointwise j
            #pragma unroll
            for (int r = 0; r < 4; ++r) {
                int rowr = j * 16 + q * 4 + r;
                float cold = s_c[rowr * CPAD + col];
                float iv = fsig (acc[j][0][r] + bf2f(ucur[r].x));
                float fv = fsig (acc[j][1][r] + bf2f(ucur[r].y));
                float gv = ftanh(acc[j][2][r] + bf2f(ucur[r].z));
                float ov = fsig (acc[j][3][r] + bf2f(ucur[r].w));
                float cn = fv * cold + iv * gv;
                float hv = ov * ftanh(cn);
                const int pos = rowr * LDA + col;
                int d = s_deg[rowr];
                if (t < d) {
                    s_c[rowr * CPAD + col] = cn;
                    nxt[pos] = (bf16_t)hv;
                } else if (t == d) {
                    reinterpret_cast<unsigned short*>(nxt)[pos] =
                        reinterpret_cast<const unsigned short*>(cur)[pos];
                }
            }
            __builtin_amdgcn_sched_barrier(0);   // region fence: cap live u at 16
        }
    };

    #pragma unroll 1
    for (int t = 0; t < tmax; ++t) {
        const bf16_t* cur = s_h[t & 1];
        bf16_t* nxt = s_h[(t + 1) & 1];
        if constexpr (RT == 4) {
            do_pass4(cur, nxt, t);
        } else {
            do_pass2(cur, nxt, t);
        }
        __syncthreads();   // nxt fully written; cur fully consumed
    }

    // final h is in s_h[tmax&1]; stage self-rows into the other buffer
    const int fb = tmax & 1;
    const bf16_t* hfin = s_h[fb];
    bf16_t* hstage = s_h[fb ^ 1];
    stage_rows<F, LDA, NT, XF32>(hstage, xself_v, s_node, tid);
    __syncthreads();

    // epilogue: out = x_self @ Wself^T + h_fin @ Wneigh^T + bout (+relu)
    constexpr int NCT = OUTF / 16;
    constexpr int TILES = NCT * 4;     // 4 row-tiles of the 64-node tile
    constexpr int TPW = TILES / NW;
    static_assert(TILES % NW == 0, "");
    #pragma unroll
    for (int tt = 0; tt < TPW; ++tt) {
        int tile = wave * TPW + tt;
        int ot = tile % NCT, rt = tile / NCT;
        f32x4 o;
        o[0] = 0.f; o[1] = 0.f; o[2] = 0.f; o[3] = 0.f;
        #pragma unroll
        for (int kk = 0; kk < KK; ++kk) {
            const int ko = kk * 32 + q * 8;
            bf16x8 axs = *reinterpret_cast<const bf16x8*>(&hstage[(rt * 16 + m16) * LDA + ko]);
            bf16x8 am  = *reinterpret_cast<const bf16x8*>(&hfin[(rt * 16 + m16) * LDA + ko]);
            bf16x8 bs = *reinterpret_cast<const bf16x8*>(Wself  + (size_t)(ot * 16 + m16) * F + ko);
            bf16x8 bn = *reinterpret_cast<const bf16x8*>(Wneigh + (size_t)(ot * 16 + m16) * F + ko);
            o = __builtin_amdgcn_mfma_f32_16x16x32_bf16(axs, bs, o, 0, 0, 0);
            o = __builtin_amdgcn_mfma_f32_16x16x32_bf16(am,  bn, o, 0, 0, 0);
        }
        int ocol = ot * 16 + m16;
        float bias = bout[ocol];
        #pragma unroll
        for (int r = 0; r < 4; ++r) {
            int node = s_node[rt * 16 + q * 4 + r];
            float v = o[r] + bias;
            if (RELU) v = fmaxf(v, 0.0f);
            outp[(size_t)node * OUTF + ocol] = (OutT)v;
        }
    }
}

extern "C" void kernel_launch(void* const* d_in, const int* in_sizes, int n_in,
                              void* d_out, int out_size, void* d_ws, size_t ws_size,
                              hipStream_t stream)
{
    const float* feat    = (const float*)d_in[0];
    const int*   nbr     = (const int*)d_in[1];
    const int*   degp    = (const int*)d_in[2];
    const float* Wih1    = (const float*)d_in[3];
    const float* Whh1    = (const float*)d_in[4];
    const float* bih1    = (const float*)d_in[5];
    const float* bhh1    = (const float*)d_in[6];
    const float* Wself1  = (const float*)d_in[7];
    const float* Wneigh1 = (const float*)d_in[8];
    const float* b1      = (const float*)d_in[9];
    const float* Wih2    = (const float*)d_in[10];
    const float* Whh2    = (const float*)d_in[11];
    const float* bih2    = (const float*)d_in[12];
    const float* bhh2    = (const float*)d_in[13];
    const float* Wself2  = (const float*)d_in[14];
    const float* Wneigh2 = (const float*)d_in[15];
    const float* b2      = (const float*)d_in[16];

    bf16_t *hglob, *wglob, *xg1, *xg2;
    int *permg;
    hipGetSymbolAddress((void**)&hglob, HIP_SYMBOL(g_hbuf));
    hipGetSymbolAddress((void**)&wglob, HIP_SYMBOL(g_wbuf));
    hipGetSymbolAddress((void**)&xg1,   HIP_SYMBOL(g_xg1));
    hipGetSymbolAddress((void**)&xg2,   HIP_SYMBOL(g_xg2));
    hipGetSymbolAddress((void**)&permg, HIP_SYMBOL(g_perm));

    cvt_weights<<<W_TOTAL / 4 / 256, 256, 0, stream>>>(
        Wih1, Whh1, Wself1, Wneigh1, Wih2, Whh2, Wself2, Wneigh2);

    build_perm<<<1, 256, 0, stream>>>(degp, permg);

    const int grid = (NN + 63) / 64;   // 469 WGs

    xg_gemm<128, 512, 8, true><<<grid, 512, 0, stream>>>(
        feat, wglob + OFF_WIH1, bih1, bhh1, xg1);

    sage_rec<128, 256, true, true, bf16_t><<<grid, 1024, 0, stream>>>(
        feat, xg1, nbr, degp, permg, wglob + OFF_WHH1,
        wglob + OFF_WSELF1, wglob + OFF_WNEIGH1, b1, hglob);

    xg_gemm<256, 1024, 8, false><<<grid, 512, 0, stream>>>(
        hglob, wglob + OFF_WIH2, bih2, bhh2, xg2);

    sage_rec<256, 64, false, false, float><<<grid, 1024, 0, stream>>>(
        hglob, xg2, nbr, degp, permg, wglob + OFF_WHH2,
        wglob + OFF_WSELF2, wglob + OFF_WNEIGH2, b2, (float*)d_out);
}